// Round 1
// 764.079 us; speedup vs baseline: 1.0995x; 1.0995x over previous
//
#include <hip/hip_runtime.h>

// ---- problem constants -----------------------------------------------------
constexpr int N_ = 64, C_ = 64, T_ = 300, V_ = 25, IC_ = 16, S_ = 3, KT_ = 9;
constexpr int RCH = 8, RSUB = 60;       // attention split-K chunks / LDS sub-chunk rows

// ---- tconv MFMA tiling ------------------------------------------------------
constexpr int TTM   = 16;               // t-steps per block
constexpr int SROWS = TTM + 8;          // staged t rows (halo 4+4)
constexpr int MROWS = SROWS * V_;       // 600 staged patch rows
constexpr int CSTR  = 40;               // LDS row stride in bf16 (32 data + 8 pad)
constexpr int NTB   = (T_ + TTM - 1) / TTM;  // 19 t-blocks

// ---- agg_out MFMA tiling ----------------------------------------------------
constexpr int TTZ   = 16;               // t-steps per block
constexpr int NTBZ  = (T_ + TTZ - 1) / TTZ;  // 19
constexpr int ASTR  = 36;               // ags row stride (32 c + 4 pad), bf16

typedef __bf16 bf16x8 __attribute__((ext_vector_type(8)));
typedef __bf16 bf16x4 __attribute__((ext_vector_type(4)));
typedef float  f32x4  __attribute__((ext_vector_type(4)));

// ---- workspace layout (floats) ----------------------------------------------
constexpr int OFF_AFULL = 0;
constexpr int SZ_AFULL  = S_ * V_ * V_;                 // 1875
constexpr int OFF_WTB   = OFF_AFULL + SZ_AFULL;         // bf16 S*9*32*64
constexpr int SZ_WTB_F  = (S_ * KT_ * 32 * C_) / 2;     // 27648 float-slots
constexpr int OFF_BTC   = OFF_WTB + SZ_WTB_F;           // S*32 fp32 biases
constexpr int OFF_WDB   = OFF_BTC + S_ * 32;            // bf16 S*64*64 [i][o][c]
constexpr int SZ_WDB_F  = (S_ * C_ * C_) / 2;           // 6144 float-slots
constexpr int OFF_BDT   = OFF_WDB + SZ_WDB_F;           // C
constexpr int OFF_BNA   = OFF_BDT + C_;
constexpr int OFF_BNB   = OFF_BNA + C_;
constexpr int OFF_A1    = OFF_BNB + C_;
constexpr int SZ_A1     = S_ * N_ * V_ * V_;            // 120000  [i][n][u][v] fp32
constexpr int OFF_SPART = OFF_A1 + SZ_A1;
constexpr int SZ_SPART  = N_ * RCH * V_ * V_;           // 320000
constexpr int OFF_T1    = OFF_SPART + SZ_SPART;
constexpr int SZ_T_F    = (N_ * IC_ * T_ * V_) / 2;     // bf16 now: 3.84M float-slots
constexpr int OFF_T2    = OFF_T1 + SZ_T_F;

// SlimConv2d channel scales: splits at int(0.6/0.7/0.8/0.9 * out_c)
__device__ __forceinline__ float slim16(const float* w, int o) {
    if (o < 9)  return 1.0f;
    if (o < 11) return w[1];
    if (o < 12) return w[2];
    if (o < 14) return w[3];
    return w[4];
}
__device__ __forceinline__ float slim64(const float* w, int o) {
    if (o < 38) return 1.0f;
    if (o < 44) return w[1];
    if (o < 51) return w[2];
    if (o < 57) return w[3];
    return w[4];
}

// ---- prep: A_full, packed bf16 weights, folded biases, BN affine ------------
__global__ void prep_kernel(const float* __restrict__ wv,  const float* __restrict__ A,
                            const float* __restrict__ PA,  const float* __restrict__ Wd,
                            const float* __restrict__ bd,  const float* __restrict__ WT1,
                            const float* __restrict__ bT1, const float* __restrict__ WT2,
                            const float* __restrict__ bT2, const float* __restrict__ gam,
                            const float* __restrict__ bet, const float* __restrict__ mu,
                            const float* __restrict__ var, float* __restrict__ ws)
{
    const int gid = blockIdx.x * blockDim.x + threadIdx.x;
    const int stride = gridDim.x * blockDim.x;
    // A_full = A + PA + 8A^4 - 4A^2 - 4A + I (elementwise powers)
    for (int idx = gid; idx < S_ * V_ * V_; idx += stride) {
        int uv = idx % (V_ * V_);
        int u = uv / V_, v = uv % V_;
        float a  = A[idx];
        float a2 = a * a;
        ws[OFF_AFULL + idx] = a + PA[idx] + 8.f * a2 * a2 - 4.f * a2 - 4.f * a
                              + (u == v ? 1.f : 0.f);
    }
    // t-conv weights: scaled bf16, layout [i][kt][o32][c]
    {
        __bf16* wtb = (__bf16*)(ws + OFF_WTB);
        for (int idx = gid; idx < S_ * KT_ * 32 * C_; idx += stride) {
            int c  = idx % C_;
            int r  = idx / C_;
            int o  = r % 32;  r /= 32;
            int kt = r % KT_;
            int i  = r / KT_;
            float val;
            if (o < IC_)
                val = slim16(wv, o) * WT1[((i * IC_ + o) * C_ + c) * KT_ + kt];
            else
                val = slim16(wv, o - IC_) * WT2[((i * IC_ + (o - IC_)) * C_ + c) * KT_ + kt];
            wtb[idx] = (__bf16)val;
        }
    }
    // combined scaled t-conv biases [i][o32]
    for (int idx = gid; idx < S_ * 32; idx += stride) {
        int i = idx / 32, o = idx % 32;
        float val = (o < IC_) ? slim16(wv, o) * bT1[i * IC_ + o]
                              : slim16(wv, o - IC_) * bT2[i * IC_ + (o - IC_)];
        ws[OFF_BTC + idx] = val;
    }
    // 1x1 conv weights: scaled bf16, [i][o][c] (B-frag layout for GEMM2)
    {
        __bf16* wdb = (__bf16*)(ws + OFF_WDB);
        for (int idx = gid; idx < S_ * C_ * C_; idx += stride) {
            int c = idx % C_;
            int o = (idx / C_) % C_;
            int i = idx / (C_ * C_);
            wdb[idx] = (__bf16)(slim64(wv, o) * Wd[(i * C_ + o) * C_ + c]);
        }
    }
    // summed scaled 1x1 bias + BN affine
    for (int idx = gid; idx < C_; idx += stride) {
        float bt = 0.f;
        for (int i = 0; i < S_; ++i) bt += slim64(wv, idx) * bd[i * C_ + idx];
        ws[OFF_BDT + idx] = bt;
        float ba = gam[idx] * rsqrtf(var[idx] + 1e-5f);
        ws[OFF_BNA + idx] = ba;
        ws[OFF_BNB + idx] = bet[idx] - mu[idx] * ba;
    }
}

// ---- kernel A: both temporal convs via MFMA implicit GEMM -------------------
__global__ __launch_bounds__(320) void tconv_mfma_kernel(
    const float* __restrict__ x,  const __bf16* __restrict__ wt,
    const float* __restrict__ bias32,
    __bf16* __restrict__ t1o, __bf16* __restrict__ t2o)
{
    __shared__ __align__(16) __bf16 xs[MROWS * CSTR];   // 48 KB
    const int tid  = threadIdx.x;
    const int n    = blockIdx.y;
    const int t0   = blockIdx.x * TTM;
    const int wv   = tid >> 6;
    const int lane = tid & 63;
    const int l15  = lane & 15;
    const int quad = lane >> 4;

    f32x4 acc[5][2];
#pragma unroll
    for (int j = 0; j < 5; ++j)
#pragma unroll
        for (int p = 0; p < 2; ++p) acc[j][p] = (f32x4){0.f, 0.f, 0.f, 0.f};

    for (int ch = 0; ch < 2; ++ch) {
        const int c0 = ch * 32;
        __syncthreads();
        for (int idx = tid; idx < MROWS * 4; idx += 320) {
            const int lr = idx % MROWS;
            const int cg = idx / MROWS;
            const int tg = t0 - 4 + lr / V_;
            bf16x8 pk;
            if (tg >= 0 && tg < T_) {
                const float* gp = x + ((size_t)(n * C_ + c0 + cg * 8) * T_ + (t0 - 4)) * V_ + lr;
#pragma unroll
                for (int jj = 0; jj < 8; ++jj) pk[jj] = (__bf16)gp[(size_t)jj * T_ * V_];
            } else {
#pragma unroll
                for (int jj = 0; jj < 8; ++jj) pk[jj] = (__bf16)0.f;
            }
            *(bf16x8*)&xs[lr * CSTR + cg * 8] = pk;
        }
        __syncthreads();

        for (int kt = 0; kt < KT_; ++kt) {
            const bf16x8 a0 = *(const bf16x8*)&wt[(kt * 32 + l15) * C_ + c0 + quad * 8];
            const bf16x8 a1 = *(const bf16x8*)&wt[(kt * 32 + 16 + l15) * C_ + c0 + quad * 8];
#pragma unroll
            for (int j = 0; j < 5; ++j) {
                const int r = (wv * 5 + j) * 16 + l15 + V_ * kt;
                const bf16x8 b = *(const bf16x8*)&xs[r * CSTR + quad * 8];
                acc[j][0] = __builtin_amdgcn_mfma_f32_16x16x32_bf16(a0, b, acc[j][0], 0, 0, 0);
                acc[j][1] = __builtin_amdgcn_mfma_f32_16x16x32_bf16(a1, b, acc[j][1], 0, 0, 0);
            }
        }
    }

#pragma unroll
    for (int j = 0; j < 5; ++j) {
        const int m = (wv * 5 + j) * 16 + l15;
        const int t = t0 + m / V_;
        const int v = m % V_;
        if (t < T_) {
#pragma unroll
            for (int p = 0; p < 2; ++p) {
#pragma unroll
                for (int r = 0; r < 4; ++r) {
                    const int o = p * 16 + quad * 4 + r;
                    const float val = acc[j][p][r] + bias32[o];
                    if (o < IC_)
                        t1o[((n * IC_ + o) * T_ + t) * V_ + v] = (__bf16)val;
                    else
                        t2o[((n * IC_ + (o - IC_)) * T_ + t) * V_ + v] = (__bf16)val;
                }
            }
        }
    }
}

// ---- kernel B1: attention partial sums S[u,v] over 600-row chunks ----------
__global__ __launch_bounds__(256) void att_partial_kernel(
    const __bf16* __restrict__ t1, const __bf16* __restrict__ t2,
    float* __restrict__ spart)
{
    __shared__ float t1s[RSUB * V_];
    __shared__ float t2s[RSUB * V_];
    const int tid = threadIdx.x;
    const int rc  = blockIdx.x;
    const int n   = blockIdx.y;
    const int p0 = tid, p1 = tid + 256, p2 = tid + 512;
    const int p2c = (p2 < V_ * V_) ? p2 : (V_ * V_ - 1);
    const int u0 = p0 / V_, v0 = p0 % V_;
    const int u1 = p1 / V_, v1 = p1 % V_;
    const int u2 = p2c / V_, v2 = p2c % V_;
    float a0 = 0.f, a1 = 0.f, a2 = 0.f;
    const int rows = (IC_ * T_) / RCH;                       // 600
    const __bf16* g1 = t1 + (size_t)n * (IC_ * T_ * V_) + rc * rows * V_;
    const __bf16* g2 = t2 + (size_t)n * (IC_ * T_ * V_) + rc * rows * V_;
    for (int sc = 0; sc < rows / RSUB; ++sc) {
        __syncthreads();
        for (int idx = tid; idx < RSUB * V_; idx += 256) {
            t1s[idx] = (float)g1[sc * RSUB * V_ + idx];
            t2s[idx] = (float)g2[sc * RSUB * V_ + idx];
        }
        __syncthreads();
        for (int r = 0; r < RSUB; ++r) {
            const float* r1 = t1s + r * V_;
            const float* r2 = t2s + r * V_;
            a0 = fmaf(r1[u0], r2[v0], a0);
            a1 = fmaf(r1[u1], r2[v1], a1);
            a2 = fmaf(r1[u2], r2[v2], a2);
        }
    }
    float* sp = spart + (n * RCH + rc) * (V_ * V_);
    sp[p0] = a0;
    sp[p1] = a1;
    if (p2 < V_ * V_) sp[p2] = a2;
}

// ---- kernel B2: combine partials, softmax over u (axis=-2), add A_full -----
__global__ __launch_bounds__(256) void att_softmax_kernel(
    const float* __restrict__ spart, const float* __restrict__ afull,
    float* __restrict__ a1o)
{
    __shared__ float Ss[V_ * V_];
    const int n = blockIdx.x;
    const int tid = threadIdx.x;
    for (int p = tid; p < V_ * V_; p += 256) {
        float s = 0.f;
        for (int rc = 0; rc < RCH; ++rc)
            s += spart[(n * RCH + rc) * (V_ * V_) + p];
        Ss[p] = s * (1.0f / (IC_ * T_));
    }
    __syncthreads();
    if (tid < V_) {
        const int v = tid;
        float m = -1e30f;
#pragma unroll
        for (int u = 0; u < V_; ++u) m = fmaxf(m, Ss[u * V_ + v]);
        float e[V_]; float es = 0.f;
#pragma unroll
        for (int u = 0; u < V_; ++u) { e[u] = expf(Ss[u * V_ + v] - m); es += e[u]; }
        const float inv = 1.0f / es;
#pragma unroll
        for (int u = 0; u < V_; ++u)
            a1o[n * (V_ * V_) + u * V_ + v] = afull[u * V_ + v] + e[u] * inv;
    }
}

// ---- kernel C: fused (x@A1_i)->1x1 conv via 2-stage MFMA, +BN+res+relu ------
// Restructured vs prior version:
//  * GEMM1 A-frags come straight from global x (lane l15 = t-row, k = u is
//    contiguous in x) -> no xt staging pass, 32 KB less LDS, held in VGPRs
//    across the 3-subset loop.
//  * a1t for all 3 subsets staged once per block (13 barriers vs 19).
//  * GEMM2 operands swapped (A = ags m-rows, B = wdb o-cols) so D rows are
//    consecutive m2 -> float4 epilogue loads/stores (full 64B lines, kills
//    the 1.43x write amplification of the scalar o-strided epilogue).
__global__ __launch_bounds__(320) void agg_out_mfma_kernel(
    const float* __restrict__ x,   const float* __restrict__ a1,
    const __bf16* __restrict__ wdb, const float* __restrict__ bdt,
    const float* __restrict__ bna, const float* __restrict__ bnb,
    float* __restrict__ out)
{
    __shared__ __align__(16) __bf16 ags[400 * ASTR];      // 28.8 KB
    __shared__ __align__(16) __bf16 a1t3[S_ * 32 * 32];   // 6 KB [i][v32][u32]
    const int tid  = threadIdx.x;
    const int n    = blockIdx.y;
    const int t0   = blockIdx.x * TTZ;
    const int wv   = tid >> 6;
    const int lane = tid & 63;
    const int l15  = lane & 15;
    const int quad = lane >> 4;

    // stage A1^T for all 3 subsets once: a1t3[i][v][u], zero-padded
    for (int idx = tid; idx < S_ * 1024; idx += 320) {
        const int i = idx >> 10;
        const int r = idx & 1023;
        const int v = r >> 5, u = r & 31;
        float val = (v < V_ && u < V_)
                  ? a1[((size_t)(i * N_ + n) * V_ + u) * V_ + v] : 0.f;
        a1t3[idx] = (__bf16)val;
    }

    f32x4 acc[5][4];
#pragma unroll
    for (int j = 0; j < 5; ++j)
#pragma unroll
        for (int ot = 0; ot < 4; ++ot) acc[j][ot] = (f32x4){0.f, 0.f, 0.f, 0.f};

    const int tg = t0 + l15;                 // GEMM1 A-row (this lane's t)
    for (int chunk = 0; chunk < 2; ++chunk) {
        const int c0 = chunk * 32;
        // load & hold this wave's GEMM1 A-frags (x rows -> bf16), reused for all i
        bf16x8 afr[7];
#pragma unroll
        for (int k = 0; k < 7; ++k) {
            const int c = wv + 5 * k;
            bf16x8 pk;
#pragma unroll
            for (int jj = 0; jj < 8; ++jj) pk[jj] = (__bf16)0.f;
            if (c < 32 && tg < T_) {
                const float* gp = x + ((size_t)(n * C_ + c0 + c) * T_ + tg) * V_;
#pragma unroll
                for (int jj = 0; jj < 8; ++jj) {
                    const int u = quad * 8 + jj;
                    if (u < V_) pk[jj] = (__bf16)gp[u];
                }
            }
            afr[k] = pk;
        }
        for (int i = 0; i < S_; ++i) {
            __syncthreads();   // a1t3 ready (first pass) / prev GEMM2 done with ags
            const bf16x8 b0 = *(const bf16x8*)&a1t3[i * 1024 + l15 * 32 + quad * 8];
            const bf16x8 b1 = *(const bf16x8*)&a1t3[i * 1024 + (16 + l15) * 32 + quad * 8];
            // GEMM1: D row = t-local (quad*4+r), col = v (l15) -> scatter to ags[m2][c]
#pragma unroll
            for (int k = 0; k < 7; ++k) {
                const int c = wv + 5 * k;
                if (c < 32) {
                    f32x4 d0 = (f32x4){0.f, 0.f, 0.f, 0.f};
                    f32x4 d1 = (f32x4){0.f, 0.f, 0.f, 0.f};
                    d0 = __builtin_amdgcn_mfma_f32_16x16x32_bf16(afr[k], b0, d0, 0, 0, 0);
                    d1 = __builtin_amdgcn_mfma_f32_16x16x32_bf16(afr[k], b1, d1, 0, 0, 0);
#pragma unroll
                    for (int r = 0; r < 4; ++r) {
                        const int tl = quad * 4 + r;
                        ags[(tl * V_ + l15) * ASTR + c] = (__bf16)d0[r];
                        if (l15 < V_ - 16)
                            ags[(tl * V_ + 16 + l15) * ASTR + c] = (__bf16)d1[r];
                    }
                }
            }
            __syncthreads();   // ags ready
            // GEMM2: A = ags rows (m2 = l15-indexed), B = wdb (o = l15-indexed)
            bf16x8 bw[4];
#pragma unroll
            for (int ot = 0; ot < 4; ++ot)
                bw[ot] = *(const bf16x8*)&wdb[(size_t)(i * C_ + ot * 16 + l15) * C_ + c0 + quad * 8];
#pragma unroll
            for (int j = 0; j < 5; ++j) {
                const int m2 = (wv * 5 + j) * 16 + l15;
                const bf16x4 lo = *(const bf16x4*)&ags[m2 * ASTR + quad * 8];
                const bf16x4 hi = *(const bf16x4*)&ags[m2 * ASTR + quad * 8 + 4];
                const bf16x8 am = __builtin_shufflevector(lo, hi, 0, 1, 2, 3, 4, 5, 6, 7);
#pragma unroll
                for (int ot = 0; ot < 4; ++ot)
                    acc[j][ot] = __builtin_amdgcn_mfma_f32_16x16x32_bf16(am, bw[ot], acc[j][ot], 0, 0, 0);
            }
        }
    }

    // epilogue: D row = m2 local (quad*4+r consecutive), col = o (l15)
    // -> 16B-aligned float4 residual loads + stores (full 64B lines per m-tile)
    const int mrem = (T_ - t0) * V_;   // valid m2 range in this t-block
#pragma unroll
    for (int ot = 0; ot < 4; ++ot) {
        const int o  = ot * 16 + l15;
        const float ba = bna[o], bb = bnb[o], bt = bdt[o];
#pragma unroll
        for (int j = 0; j < 5; ++j) {
            const int m2b = (wv * 5 + j) * 16 + quad * 4;
            if (m2b + 3 < mrem) {
                const size_t gi = (size_t)(n * C_ + o) * (T_ * V_) + (size_t)t0 * V_ + m2b;
                const f32x4 xr = *(const f32x4*)&x[gi];
                f32x4 rs;
#pragma unroll
                for (int r = 0; r < 4; ++r)
                    rs[r] = fmaxf(fmaf(acc[j][ot][r] + bt, ba, bb) + xr[r], 0.f);
                *(f32x4*)&out[gi] = rs;
            }
        }
    }
}

// ---- launch ----------------------------------------------------------------
extern "C" void kernel_launch(void* const* d_in, const int* in_sizes, int n_in,
                              void* d_out, int out_size, void* d_ws, size_t ws_size,
                              hipStream_t stream)
{
    (void)in_sizes; (void)n_in; (void)out_size; (void)ws_size;
    const float* x    = (const float*)d_in[0];
    const float* wv   = (const float*)d_in[1];
    const float* A    = (const float*)d_in[2];
    const float* PA   = (const float*)d_in[3];
    const float* Wd   = (const float*)d_in[4];
    const float* bd   = (const float*)d_in[5];
    const float* WT1  = (const float*)d_in[6];
    const float* bT1  = (const float*)d_in[7];
    const float* WT2  = (const float*)d_in[8];
    const float* bT2  = (const float*)d_in[9];
    const float* gam  = (const float*)d_in[10];
    const float* bet  = (const float*)d_in[11];
    const float* mu   = (const float*)d_in[12];
    const float* var  = (const float*)d_in[13];
    float* ws  = (float*)d_ws;
    float* out = (float*)d_out;

    prep_kernel<<<dim3(64), dim3(256), 0, stream>>>(
        wv, A, PA, Wd, bd, WT1, bT1, WT2, bT2, gam, bet, mu, var, ws);

    const __bf16* wtb = (const __bf16*)(ws + OFF_WTB);
    __bf16* t1b = (__bf16*)(ws + OFF_T1);
    __bf16* t2b = (__bf16*)(ws + OFF_T2);
    for (int i = 0; i < S_; ++i) {
        tconv_mfma_kernel<<<dim3(NTB, N_), dim3(320), 0, stream>>>(
            x,
            wtb + (size_t)i * KT_ * 32 * C_,
            ws + OFF_BTC + i * 32,
            t1b, t2b);
        att_partial_kernel<<<dim3(RCH, N_), dim3(256), 0, stream>>>(
            t1b, t2b, ws + OFF_SPART);
        att_softmax_kernel<<<dim3(N_), dim3(256), 0, stream>>>(
            ws + OFF_SPART, ws + OFF_AFULL + i * (V_ * V_),
            ws + OFF_A1 + i * (N_ * V_ * V_));
    }

    agg_out_mfma_kernel<<<dim3(NTBZ, N_), dim3(320), 0, stream>>>(
        x, ws + OFF_A1, (const __bf16*)(ws + OFF_WDB),
        ws + OFF_BDT, ws + OFF_BNA, ws + OFF_BNB, out);
}

// Round 2
// 552.039 us; speedup vs baseline: 1.5219x; 1.3841x over previous
//
#include <hip/hip_runtime.h>

// ---- problem constants -----------------------------------------------------
constexpr int N_ = 64, C_ = 64, T_ = 300, V_ = 25, IC_ = 16, S_ = 3, KT_ = 9;

// ---- tconv MFMA tiling ------------------------------------------------------
constexpr int TTM   = 16;               // t-steps per block
constexpr int SROWS = TTM + 8;          // staged t rows (halo 4+4)
constexpr int MROWS = SROWS * V_;       // 600 staged patch rows
constexpr int CSTR  = 40;               // LDS row stride in bf16 (32 data + 8 pad)
constexpr int NTB   = (T_ + TTM - 1) / TTM;  // 19 t-blocks
constexpr int KS_   = 264;              // S-stage t-frag K stride (256 data + 8 pad)

// ---- agg_out MFMA tiling ----------------------------------------------------
constexpr int TTZ   = 16;               // t-steps per block
constexpr int NTBZ  = (T_ + TTZ - 1) / TTZ;  // 19
constexpr int ASTR  = 36;               // ags row stride (32 c + 4 pad), bf16

typedef __bf16 bf16x8 __attribute__((ext_vector_type(8)));
typedef __bf16 bf16x4 __attribute__((ext_vector_type(4)));
typedef float  f32x4  __attribute__((ext_vector_type(4)));

// ---- workspace layout (floats) ----------------------------------------------
constexpr int OFF_AFULL = 0;
constexpr int SZ_AFULL  = S_ * V_ * V_;                 // 1875
constexpr int OFF_WTB   = OFF_AFULL + SZ_AFULL;         // bf16 S*9*32*64
constexpr int SZ_WTB_F  = (S_ * KT_ * 32 * C_) / 2;     // 27648 float-slots
constexpr int OFF_BTC   = OFF_WTB + SZ_WTB_F;           // S*32 fp32 biases
constexpr int OFF_WDB   = OFF_BTC + S_ * 32;            // bf16 S*64*64 [i][o][c]
constexpr int SZ_WDB_F  = (S_ * C_ * C_) / 2;           // 6144 float-slots
constexpr int OFF_BDT   = OFF_WDB + SZ_WDB_F;           // C
constexpr int OFF_BNA   = OFF_BDT + C_;
constexpr int OFF_BNB   = OFF_BNA + C_;
constexpr int OFF_A1    = OFF_BNB + C_;
constexpr int SZ_A1     = S_ * N_ * V_ * V_;            // 120000  [i][n][u][v] fp32
constexpr int OFF_SPART = OFF_A1 + SZ_A1;
constexpr int SZ_SPART  = S_ * N_ * NTB * V_ * V_;      // 2.28M [i][n][blk][u][v]

// SlimConv2d channel scales: splits at int(0.6/0.7/0.8/0.9 * out_c)
__device__ __forceinline__ float slim16(const float* w, int o) {
    if (o < 9)  return 1.0f;
    if (o < 11) return w[1];
    if (o < 12) return w[2];
    if (o < 14) return w[3];
    return w[4];
}
__device__ __forceinline__ float slim64(const float* w, int o) {
    if (o < 38) return 1.0f;
    if (o < 44) return w[1];
    if (o < 51) return w[2];
    if (o < 57) return w[3];
    return w[4];
}

// ---- prep: A_full, packed bf16 weights, folded biases, BN affine ------------
__global__ void prep_kernel(const float* __restrict__ wv,  const float* __restrict__ A,
                            const float* __restrict__ PA,  const float* __restrict__ Wd,
                            const float* __restrict__ bd,  const float* __restrict__ WT1,
                            const float* __restrict__ bT1, const float* __restrict__ WT2,
                            const float* __restrict__ bT2, const float* __restrict__ gam,
                            const float* __restrict__ bet, const float* __restrict__ mu,
                            const float* __restrict__ var, float* __restrict__ ws)
{
    const int gid = blockIdx.x * blockDim.x + threadIdx.x;
    const int stride = gridDim.x * blockDim.x;
    // A_full = A + PA + 8A^4 - 4A^2 - 4A + I (elementwise powers)
    for (int idx = gid; idx < S_ * V_ * V_; idx += stride) {
        int uv = idx % (V_ * V_);
        int u = uv / V_, v = uv % V_;
        float a  = A[idx];
        float a2 = a * a;
        ws[OFF_AFULL + idx] = a + PA[idx] + 8.f * a2 * a2 - 4.f * a2 - 4.f * a
                              + (u == v ? 1.f : 0.f);
    }
    // t-conv weights: scaled bf16, layout [i][kt][o32][c]
    {
        __bf16* wtb = (__bf16*)(ws + OFF_WTB);
        for (int idx = gid; idx < S_ * KT_ * 32 * C_; idx += stride) {
            int c  = idx % C_;
            int r  = idx / C_;
            int o  = r % 32;  r /= 32;
            int kt = r % KT_;
            int i  = r / KT_;
            float val;
            if (o < IC_)
                val = slim16(wv, o) * WT1[((i * IC_ + o) * C_ + c) * KT_ + kt];
            else
                val = slim16(wv, o - IC_) * WT2[((i * IC_ + (o - IC_)) * C_ + c) * KT_ + kt];
            wtb[idx] = (__bf16)val;
        }
    }
    // combined scaled t-conv biases [i][o32]
    for (int idx = gid; idx < S_ * 32; idx += stride) {
        int i = idx / 32, o = idx % 32;
        float val = (o < IC_) ? slim16(wv, o) * bT1[i * IC_ + o]
                              : slim16(wv, o - IC_) * bT2[i * IC_ + (o - IC_)];
        ws[OFF_BTC + idx] = val;
    }
    // 1x1 conv weights: scaled bf16, [i][o][c] (B-frag layout for GEMM2)
    {
        __bf16* wdb = (__bf16*)(ws + OFF_WDB);
        for (int idx = gid; idx < S_ * C_ * C_; idx += stride) {
            int c = idx % C_;
            int o = (idx / C_) % C_;
            int i = idx / (C_ * C_);
            wdb[idx] = (__bf16)(slim64(wv, o) * Wd[(i * C_ + o) * C_ + c]);
        }
    }
    // summed scaled 1x1 bias + BN affine
    for (int idx = gid; idx < C_; idx += stride) {
        float bt = 0.f;
        for (int i = 0; i < S_; ++i) bt += slim64(wv, idx) * bd[i * C_ + idx];
        ws[OFF_BDT + idx] = bt;
        float ba = gam[idx] * rsqrtf(var[idx] + 1e-5f);
        ws[OFF_BNA + idx] = ba;
        ws[OFF_BNB + idx] = bet[idx] - mu[idx] * ba;
    }
}

// ---- kernel A: all 3 subsets' temporal convs + attention partials, fused ----
// Phase 1: implicit-GEMM conv via MFMA. x staged to LDS ONCE per (n, t-block),
//   all 6 output o-tiles (3 subsets x {t1,t2}) accumulate in registers.
// Phase 2 (per subset): acc (+bias, ->bf16) rearranged into K-major LDS frags
//   t1L[u][k], t2L[v][k] (k = ic*16 + t_local, K=256), then a 2nd MFMA stage
//   computes the 25x25 partial S[u,v] for this t-block -> spart (fp32).
// t1/t2 never touch HBM.
__global__ __launch_bounds__(320) void tconv_att_kernel(
    const float* __restrict__ x,  const __bf16* __restrict__ wt,
    const float* __restrict__ btc, float* __restrict__ spart)
{
    __shared__ __align__(16) char lds_raw[MROWS * CSTR * 2];   // 48 KB
    __bf16* xs  = (__bf16*)lds_raw;                 // [600][40] conv staging
    __bf16* t1L = (__bf16*)lds_raw;                 // [32][KS_] S-stage (union)
    __bf16* t2L = t1L + 32 * KS_;
    const int tid  = threadIdx.x;
    const int n    = blockIdx.y;
    const int tb   = blockIdx.x;
    const int t0   = tb * TTM;
    const int wv   = tid >> 6;
    const int lane = tid & 63;
    const int l15  = lane & 15;
    const int quad = lane >> 4;

    f32x4 acc[5][6];
#pragma unroll
    for (int j = 0; j < 5; ++j)
#pragma unroll
        for (int p = 0; p < 6; ++p) acc[j][p] = (f32x4){0.f, 0.f, 0.f, 0.f};

    for (int ch = 0; ch < 2; ++ch) {
        const int c0 = ch * 32;
        __syncthreads();
        for (int idx = tid; idx < MROWS * 4; idx += 320) {
            const int lr = idx % MROWS;
            const int cg = idx / MROWS;
            const int tg = t0 - 4 + lr / V_;
            bf16x8 pk;
            if (tg >= 0 && tg < T_) {
                const float* gp = x + ((size_t)(n * C_ + c0 + cg * 8) * T_ + (t0 - 4)) * V_ + lr;
#pragma unroll
                for (int jj = 0; jj < 8; ++jj) pk[jj] = (__bf16)gp[(size_t)jj * T_ * V_];
            } else {
#pragma unroll
                for (int jj = 0; jj < 8; ++jj) pk[jj] = (__bf16)0.f;
            }
            *(bf16x8*)&xs[lr * CSTR + cg * 8] = pk;
        }
        __syncthreads();

        for (int kt = 0; kt < KT_; ++kt) {
            bf16x8 a[6];
#pragma unroll
            for (int p = 0; p < 6; ++p) {
                const int i = p >> 1, h = p & 1;
                a[p] = *(const bf16x8*)&wt[((size_t)((i * KT_ + kt) * 32 + h * 16 + l15)) * C_ + c0 + quad * 8];
            }
#pragma unroll
            for (int j = 0; j < 5; ++j) {
                const int r = (wv * 5 + j) * 16 + l15 + V_ * kt;
                const bf16x8 b = *(const bf16x8*)&xs[r * CSTR + quad * 8];
#pragma unroll
                for (int p = 0; p < 6; ++p)
                    acc[j][p] = __builtin_amdgcn_mfma_f32_16x16x32_bf16(a[p], b, acc[j][p], 0, 0, 0);
            }
        }
    }

    // ---- Phase 2: per-subset attention partial S[u,v] over this t-block ----
    for (int i = 0; i < S_; ++i) {
        __syncthreads();   // conv LDS reads done (i=0) / prev S-MFMA done (i>0)
        // rearrange acc -> K-major bf16 frags: t1L[u][o*16+tl], t2L[v][o*16+tl]
#pragma unroll
        for (int j = 0; j < 5; ++j) {
            const int m  = (wv * 5 + j) * 16 + l15;
            const int tl = m / V_;
            const int u  = m % V_;
            const bool valid = (t0 + tl) < T_;
#pragma unroll
            for (int h = 0; h < 2; ++h) {
                const int p = i * 2 + h;
                __bf16* dst = h ? t2L : t1L;
#pragma unroll
                for (int r = 0; r < 4; ++r) {
                    const int o = quad * 4 + r;
                    const float val = valid ? (acc[j][p][r] + btc[i * 32 + h * 16 + o]) : 0.f;
                    dst[u * KS_ + o * 16 + tl] = (__bf16)val;
                }
            }
        }
        __syncthreads();   // frags ready
        if (wv < 4) {
            const int ut = wv >> 1, vt = wv & 1;
            f32x4 sa = (f32x4){0.f, 0.f, 0.f, 0.f};
#pragma unroll
            for (int ks = 0; ks < 8; ++ks) {
                const bf16x8 A = *(const bf16x8*)&t1L[(ut * 16 + l15) * KS_ + ks * 32 + quad * 8];
                const bf16x8 B = *(const bf16x8*)&t2L[(vt * 16 + l15) * KS_ + ks * 32 + quad * 8];
                sa = __builtin_amdgcn_mfma_f32_16x16x32_bf16(A, B, sa, 0, 0, 0);
            }
            float* sp = spart + (((size_t)i * N_ + n) * NTB + tb) * (V_ * V_);
#pragma unroll
            for (int r = 0; r < 4; ++r) {
                const int u = ut * 16 + quad * 4 + r;
                const int v = vt * 16 + l15;
                if (u < V_ && v < V_) sp[u * V_ + v] = sa[r];
            }
        }
    }
}

// ---- kernel B: combine partials, softmax over u (axis=-2), add A_full ------
__global__ __launch_bounds__(256) void att_softmax_kernel(
    const float* __restrict__ spart, const float* __restrict__ afull,
    float* __restrict__ a1o)
{
    __shared__ float Ss[V_ * V_];
    const int n = blockIdx.x;
    const int i = blockIdx.y;
    const int tid = threadIdx.x;
    for (int p = tid; p < V_ * V_; p += 256) {
        float s = 0.f;
        const float* sp = spart + (((size_t)i * N_ + n) * NTB) * (V_ * V_) + p;
        for (int blk = 0; blk < NTB; ++blk)
            s += sp[(size_t)blk * (V_ * V_)];
        Ss[p] = s * (1.0f / (IC_ * T_));
    }
    __syncthreads();
    if (tid < V_) {
        const int v = tid;
        float m = -1e30f;
#pragma unroll
        for (int u = 0; u < V_; ++u) m = fmaxf(m, Ss[u * V_ + v]);
        float e[V_]; float es = 0.f;
#pragma unroll
        for (int u = 0; u < V_; ++u) { e[u] = expf(Ss[u * V_ + v] - m); es += e[u]; }
        const float inv = 1.0f / es;
#pragma unroll
        for (int u = 0; u < V_; ++u)
            a1o[((size_t)i * N_ + n) * (V_ * V_) + u * V_ + v]
                = afull[i * (V_ * V_) + u * V_ + v] + e[u] * inv;
    }
}

// ---- kernel C: fused (x@A1_i)->1x1 conv via 2-stage MFMA, +BN+res+relu ------
__global__ __launch_bounds__(320) void agg_out_mfma_kernel(
    const float* __restrict__ x,   const float* __restrict__ a1,
    const __bf16* __restrict__ wdb, const float* __restrict__ bdt,
    const float* __restrict__ bna, const float* __restrict__ bnb,
    float* __restrict__ out)
{
    __shared__ __align__(16) __bf16 ags[400 * ASTR];      // 28.8 KB
    __shared__ __align__(16) __bf16 a1t3[S_ * 32 * 32];   // 6 KB [i][v32][u32]
    const int tid  = threadIdx.x;
    const int n    = blockIdx.y;
    const int t0   = blockIdx.x * TTZ;
    const int wv   = tid >> 6;
    const int lane = tid & 63;
    const int l15  = lane & 15;
    const int quad = lane >> 4;

    // stage A1^T for all 3 subsets once: a1t3[i][v][u], zero-padded
    for (int idx = tid; idx < S_ * 1024; idx += 320) {
        const int i = idx >> 10;
        const int r = idx & 1023;
        const int v = r >> 5, u = r & 31;
        float val = (v < V_ && u < V_)
                  ? a1[((size_t)(i * N_ + n) * V_ + u) * V_ + v] : 0.f;
        a1t3[idx] = (__bf16)val;
    }

    f32x4 acc[5][4];
#pragma unroll
    for (int j = 0; j < 5; ++j)
#pragma unroll
        for (int ot = 0; ot < 4; ++ot) acc[j][ot] = (f32x4){0.f, 0.f, 0.f, 0.f};

    const int tg = t0 + l15;                 // GEMM1 A-row (this lane's t)
    for (int chunk = 0; chunk < 2; ++chunk) {
        const int c0 = chunk * 32;
        // load & hold this wave's GEMM1 A-frags (x rows -> bf16), reused for all i
        bf16x8 afr[7];
#pragma unroll
        for (int k = 0; k < 7; ++k) {
            const int c = wv + 5 * k;
            bf16x8 pk;
#pragma unroll
            for (int jj = 0; jj < 8; ++jj) pk[jj] = (__bf16)0.f;
            if (c < 32 && tg < T_) {
                const float* gp = x + ((size_t)(n * C_ + c0 + c) * T_ + tg) * V_;
#pragma unroll
                for (int jj = 0; jj < 8; ++jj) {
                    const int u = quad * 8 + jj;
                    if (u < V_) pk[jj] = (__bf16)gp[u];
                }
            }
            afr[k] = pk;
        }
        for (int i = 0; i < S_; ++i) {
            __syncthreads();   // a1t3 ready (first pass) / prev GEMM2 done with ags
            const bf16x8 b0 = *(const bf16x8*)&a1t3[i * 1024 + l15 * 32 + quad * 8];
            const bf16x8 b1 = *(const bf16x8*)&a1t3[i * 1024 + (16 + l15) * 32 + quad * 8];
            // GEMM1: D row = t-local (quad*4+r), col = v (l15) -> scatter to ags[m2][c]
#pragma unroll
            for (int k = 0; k < 7; ++k) {
                const int c = wv + 5 * k;
                if (c < 32) {
                    f32x4 d0 = (f32x4){0.f, 0.f, 0.f, 0.f};
                    f32x4 d1 = (f32x4){0.f, 0.f, 0.f, 0.f};
                    d0 = __builtin_amdgcn_mfma_f32_16x16x32_bf16(afr[k], b0, d0, 0, 0, 0);
                    d1 = __builtin_amdgcn_mfma_f32_16x16x32_bf16(afr[k], b1, d1, 0, 0, 0);
#pragma unroll
                    for (int r = 0; r < 4; ++r) {
                        const int tl = quad * 4 + r;
                        ags[(tl * V_ + l15) * ASTR + c] = (__bf16)d0[r];
                        if (l15 < V_ - 16)
                            ags[(tl * V_ + 16 + l15) * ASTR + c] = (__bf16)d1[r];
                    }
                }
            }
            __syncthreads();   // ags ready
            // GEMM2: A = ags rows (m2 = l15-indexed), B = wdb (o = l15-indexed)
            bf16x8 bw[4];
#pragma unroll
            for (int ot = 0; ot < 4; ++ot)
                bw[ot] = *(const bf16x8*)&wdb[(size_t)(i * C_ + ot * 16 + l15) * C_ + c0 + quad * 8];
#pragma unroll
            for (int j = 0; j < 5; ++j) {
                const int m2 = (wv * 5 + j) * 16 + l15;
                const bf16x4 lo = *(const bf16x4*)&ags[m2 * ASTR + quad * 8];
                const bf16x4 hi = *(const bf16x4*)&ags[m2 * ASTR + quad * 8 + 4];
                const bf16x8 am = __builtin_shufflevector(lo, hi, 0, 1, 2, 3, 4, 5, 6, 7);
#pragma unroll
                for (int ot = 0; ot < 4; ++ot)
                    acc[j][ot] = __builtin_amdgcn_mfma_f32_16x16x32_bf16(am, bw[ot], acc[j][ot], 0, 0, 0);
            }
        }
    }

    // epilogue: D row = m2 local (quad*4+r consecutive), col = o (l15)
    const int mrem = (T_ - t0) * V_;   // valid m2 range in this t-block
#pragma unroll
    for (int ot = 0; ot < 4; ++ot) {
        const int o  = ot * 16 + l15;
        const float ba = bna[o], bb = bnb[o], bt = bdt[o];
#pragma unroll
        for (int j = 0; j < 5; ++j) {
            const int m2b = (wv * 5 + j) * 16 + quad * 4;
            if (m2b + 3 < mrem) {
                const size_t gi = (size_t)(n * C_ + o) * (T_ * V_) + (size_t)t0 * V_ + m2b;
                const f32x4 xr = *(const f32x4*)&x[gi];
                f32x4 rs;
#pragma unroll
                for (int r = 0; r < 4; ++r)
                    rs[r] = fmaxf(fmaf(acc[j][ot][r] + bt, ba, bb) + xr[r], 0.f);
                *(f32x4*)&out[gi] = rs;
            }
        }
    }
}

// ---- launch ----------------------------------------------------------------
extern "C" void kernel_launch(void* const* d_in, const int* in_sizes, int n_in,
                              void* d_out, int out_size, void* d_ws, size_t ws_size,
                              hipStream_t stream)
{
    (void)in_sizes; (void)n_in; (void)out_size; (void)ws_size;
    const float* x    = (const float*)d_in[0];
    const float* wv   = (const float*)d_in[1];
    const float* A    = (const float*)d_in[2];
    const float* PA   = (const float*)d_in[3];
    const float* Wd   = (const float*)d_in[4];
    const float* bd   = (const float*)d_in[5];
    const float* WT1  = (const float*)d_in[6];
    const float* bT1  = (const float*)d_in[7];
    const float* WT2  = (const float*)d_in[8];
    const float* bT2  = (const float*)d_in[9];
    const float* gam  = (const float*)d_in[10];
    const float* bet  = (const float*)d_in[11];
    const float* mu   = (const float*)d_in[12];
    const float* var  = (const float*)d_in[13];
    float* ws  = (float*)d_ws;
    float* out = (float*)d_out;

    prep_kernel<<<dim3(64), dim3(256), 0, stream>>>(
        wv, A, PA, Wd, bd, WT1, bT1, WT2, bT2, gam, bet, mu, var, ws);

    tconv_att_kernel<<<dim3(NTB, N_), dim3(320), 0, stream>>>(
        x, (const __bf16*)(ws + OFF_WTB), ws + OFF_BTC, ws + OFF_SPART);

    att_softmax_kernel<<<dim3(N_, S_), dim3(256), 0, stream>>>(
        ws + OFF_SPART, ws + OFF_AFULL, ws + OFF_A1);

    agg_out_mfma_kernel<<<dim3(NTBZ, N_), dim3(320), 0, stream>>>(
        x, ws + OFF_A1, (const __bf16*)(ws + OFF_WDB),
        ws + OFF_BDT, ws + OFF_BNA, ws + OFF_BNB, out);
}